// Round 1
// baseline (1340.496 us; speedup 1.0000x reference)
//
#include <hip/hip_runtime.h>

typedef __attribute__((ext_vector_type(8))) short short8;
typedef __attribute__((ext_vector_type(4))) float f32x4;

#define DIM 128
#define RREL 32
#define TM 64

__device__ __forceinline__ ushort f2bf(float f) {
    unsigned u = __builtin_bit_cast(unsigned, f);
    u = (u + 0x7FFFu + ((u >> 16) & 1u)) >> 16;
    return (ushort)u;
}

// Wt[l][r][n][k] = sum_b coeff[l,r,b] * basis[l,b,k,n]   (bf16, transposed for MFMA B-frag)
__global__ __launch_bounds__(256) void build_w_kernel(const float* __restrict__ coeff,
                                                      const float* __restrict__ basis,
                                                      ushort* __restrict__ Wt) {
    int idx = blockIdx.x * 256 + threadIdx.x;   // [l][r][n][k], k fast
    int k = idx & 127;
    int n = (idx >> 7) & 127;
    int lr = idx >> 14;                          // l*32 + r
    int l = lr >> 5;
    const float* cb = coeff + lr * 8;
    const float* bb = basis + (size_t)l * 8 * 16384 + k * 128 + n;
    float s = 0.f;
#pragma unroll
    for (int b = 0; b < 8; ++b) s += cb[b] * bb[(size_t)b * 16384];
    Wt[idx] = f2bf(s);
}

__global__ __launch_bounds__(256) void tobf16_kernel(const float* __restrict__ in,
                                                     ushort* __restrict__ out, int n8) {
    int i = blockIdx.x * 256 + threadIdx.x;
    if (i >= n8) return;
    const float4* p = (const float4*)in + 2 * (size_t)i;
    float4 a = p[0], b = p[1];
    unsigned w0 = f2bf(a.x) | ((unsigned)f2bf(a.y) << 16);
    unsigned w1 = f2bf(a.z) | ((unsigned)f2bf(a.w) << 16);
    unsigned w2 = f2bf(b.x) | ((unsigned)f2bf(b.y) << 16);
    unsigned w3 = f2bf(b.z) | ((unsigned)f2bf(b.w) << 16);
    ((uint4*)out)[i] = make_uint4(w0, w1, w2, w3);
}

__global__ __launch_bounds__(256) void hist_kernel(const int* __restrict__ et, int E,
                                                   int* __restrict__ hist) {
    __shared__ int lh[RREL];
    if (threadIdx.x < RREL) lh[threadIdx.x] = 0;
    __syncthreads();
    for (int i = blockIdx.x * 256 + threadIdx.x; i < E; i += gridDim.x * 256)
        atomicAdd(&lh[et[i]], 1);
    __syncthreads();
    if (threadIdx.x < RREL) atomicAdd(&hist[threadIdx.x], lh[threadIdx.x]);
}

__global__ void scan_kernel(const int* __restrict__ hist, int* __restrict__ offsets,
                            int* __restrict__ cursor, int2* __restrict__ tiles,
                            int* __restrict__ ntiles) {
    __shared__ int off[RREL + 1];
    __shared__ int ts[RREL + 1];
    if (threadIdx.x == 0) {
        int s = 0, t = 0;
        for (int r = 0; r < RREL; ++r) {
            off[r] = s; ts[r] = t;
            s += hist[r]; t += (hist[r] + TM - 1) / TM;
        }
        off[RREL] = s; ts[RREL] = t;
        *ntiles = t;
    }
    __syncthreads();
    int r = threadIdx.x;
    if (r < RREL) {
        offsets[r] = off[r];
        cursor[r] = off[r];
        int nt = ts[r + 1] - ts[r];
        for (int i = 0; i < nt; ++i) tiles[ts[r] + i] = make_int2(r, off[r] + i * TM);
    }
    if (r == 0) offsets[RREL] = off[RREL];
}

__global__ __launch_bounds__(256) void scatter_kernel(const int* __restrict__ src,
                                                      const int* __restrict__ dst,
                                                      const int* __restrict__ et,
                                                      const float* __restrict__ norm, int E,
                                                      int* __restrict__ cursor,
                                                      int* __restrict__ src_s,
                                                      int* __restrict__ dst_s,
                                                      float* __restrict__ norm_s) {
    __shared__ int lh[RREL];
    __shared__ int lbase[RREL];
    int i = blockIdx.x * 256 + threadIdx.x;
    if (threadIdx.x < RREL) lh[threadIdx.x] = 0;
    __syncthreads();
    int r = 0, rank = 0;
    bool valid = (i < E);
    if (valid) { r = et[i]; rank = atomicAdd(&lh[r], 1); }
    __syncthreads();
    if (threadIdx.x < RREL) {
        int c = lh[threadIdx.x];
        if (c > 0) lbase[threadIdx.x] = atomicAdd(&cursor[threadIdx.x], c);
    }
    __syncthreads();
    if (valid) {
        int p = lbase[r] + rank;
        src_s[p] = src[i]; dst_s[p] = dst[i]; norm_s[p] = norm[i];
    }
}

// One block = one (relation, 64-edge) tile: msg = gather(h)[64x128] @ W_r[128x128], *norm, atomic into agg[dst]
__global__ __launch_bounds__(256) void gemm_scatter_kernel(
    const ushort* __restrict__ hb, const ushort* __restrict__ Wt,
    const int* __restrict__ src_s, const int* __restrict__ dst_s,
    const float* __restrict__ norm_s, const int2* __restrict__ tiles,
    const int* __restrict__ ntiles, const int* __restrict__ offsets,
    float* __restrict__ agg) {
    __shared__ ushort Alds[TM * DIM];    // swizzled: idx16 = (row*16+ci) ^ (row&7)
    __shared__ ushort Blds[DIM * DIM];   // [n][k] swizzled: idx16 = (n*16+ci) ^ (n&7)
    __shared__ int dstl[TM];
    __shared__ float morml[TM];

    int bx = blockIdx.x;
    if (bx >= *ntiles) return;
    int2 ti = tiles[bx];
    int r = ti.x, row0 = ti.y;
    int rows = offsets[r + 1] - row0;
    if (rows > TM) rows = TM;

    int t = threadIdx.x;
    if (t < rows) { dstl[t] = dst_s[row0 + t]; morml[t] = norm_s[row0 + t]; }

    const int4* Wg = (const int4*)(Wt + (size_t)r * DIM * DIM);
    int4* Bv = (int4*)Blds;
#pragma unroll
    for (int c = t; c < DIM * DIM / 8; c += 256) {   // 2048 16B chunks
        int n = c >> 4, ci = c & 15;
        Bv[(n * 16 + ci) ^ (n & 7)] = Wg[c];
    }
    int4* Av = (int4*)Alds;
#pragma unroll
    for (int c = t; c < TM * DIM / 8; c += 256) {    // 1024 16B chunks
        int row = c >> 4, ci = c & 15;
        int e = row0 + (row < rows ? row : rows - 1);
        int s = src_s[e];
        Av[(row * 16 + ci) ^ (row & 7)] = ((const int4*)(hb + (size_t)s * DIM))[ci];
    }
    __syncthreads();

    int w = t >> 6, l = t & 63;
    int wr = w & 1, wc = w >> 1;          // 2x2 wave grid: 32 rows x 64 cols per wave
    int lr16 = l & 15, lhi = l >> 4;

    f32x4 acc[2][4];
#pragma unroll
    for (int m = 0; m < 2; ++m)
#pragma unroll
        for (int n16 = 0; n16 < 4; ++n16) acc[m][n16] = (f32x4)0.f;

    const short8* As = (const short8*)Alds;
    const short8* Bs = (const short8*)Blds;
#pragma unroll
    for (int k4 = 0; k4 < 4; ++k4) {
        int kc = k4 * 4 + lhi;
        int ar0 = wr * 32 + lr16;
        int ar1 = ar0 + 16;
        short8 a0 = As[(ar0 * 16 + kc) ^ (ar0 & 7)];
        short8 a1 = As[(ar1 * 16 + kc) ^ (ar1 & 7)];
#pragma unroll
        for (int n16 = 0; n16 < 4; ++n16) {
            int n = wc * 64 + n16 * 16 + lr16;
            short8 b = Bs[(n * 16 + kc) ^ (n & 7)];
            acc[0][n16] = __builtin_amdgcn_mfma_f32_16x16x32_bf16(a0, b, acc[0][n16], 0, 0, 0);
            acc[1][n16] = __builtin_amdgcn_mfma_f32_16x16x32_bf16(a1, b, acc[1][n16], 0, 0, 0);
        }
    }

#pragma unroll
    for (int m = 0; m < 2; ++m) {
#pragma unroll
        for (int j = 0; j < 4; ++j) {
            int row = wr * 32 + m * 16 + lhi * 4 + j;
            if (row < rows) {
                float nm = morml[row];
                float* ag = agg + (size_t)dstl[row] * DIM;
#pragma unroll
                for (int n16 = 0; n16 < 4; ++n16) {
                    int col = wc * 64 + n16 * 16 + lr16;
                    atomicAdd(ag + col, acc[m][n16][j] * nm);
                }
            }
        }
    }
}

__global__ __launch_bounds__(256) void bias_relu_kernel(const float* __restrict__ agg,
                                                        const float* __restrict__ bias,
                                                        float* __restrict__ of32,
                                                        ushort* __restrict__ obf, int n4) {
    int i = blockIdx.x * 256 + threadIdx.x;
    if (i >= n4) return;
    float4 v = ((const float4*)agg)[i];
    int col = (i << 2) & 127;
    v.x = fmaxf(v.x + bias[col], 0.f);
    v.y = fmaxf(v.y + bias[col + 1], 0.f);
    v.z = fmaxf(v.z + bias[col + 2], 0.f);
    v.w = fmaxf(v.w + bias[col + 3], 0.f);
    if (of32) ((float4*)of32)[i] = v;
    if (obf) {
        unsigned w0 = f2bf(v.x) | ((unsigned)f2bf(v.y) << 16);
        unsigned w1 = f2bf(v.z) | ((unsigned)f2bf(v.w) << 16);
        ((uint2*)obf)[i] = make_uint2(w0, w1);
    }
}

__global__ __launch_bounds__(256) void gather_kernel(const float* __restrict__ p_h,
                                                     const float* __restrict__ n_h,
                                                     const float* __restrict__ w_rel,
                                                     const int* __restrict__ pg_head,
                                                     const int* __restrict__ pg_tail,
                                                     const int* __restrict__ pg_et,
                                                     const int* __restrict__ ng_head,
                                                     const int* __restrict__ ng_tail,
                                                     float* __restrict__ out, int P) {
    long tid = (long)blockIdx.x * 256 + threadIdx.x;
    long total = (long)5 * P * 32;
    if (tid >= total) return;
    int c = (int)(tid & 31);
    long rest = tid >> 5;
    int i = (int)(rest % P);
    int which = (int)(rest / P);
    const float* srcp; int row;
    switch (which) {
        case 0: srcp = p_h;   row = pg_head[i]; break;
        case 1: srcp = p_h;   row = pg_tail[i]; break;
        case 2: srcp = w_rel; row = pg_et[i];   break;
        case 3: srcp = n_h;   row = ng_head[i]; break;
        default: srcp = n_h;  row = ng_tail[i]; break;
    }
    float4 v = ((const float4*)(srcp + (size_t)row * DIM))[c];
    ((float4*)out)[((size_t)which * P + i) * 32 + c] = v;
}

extern "C" void kernel_launch(void* const* d_in, const int* in_sizes, int n_in,
                              void* d_out, int out_size, void* d_ws, size_t ws_size,
                              hipStream_t stream) {
    const float* feats[2] = {(const float*)d_in[0], (const float*)d_in[1]};
    const float* w_relation = (const float*)d_in[2];
    const float* coeff = (const float*)d_in[3];
    const float* basis = (const float*)d_in[4];
    const float* bias = (const float*)d_in[5];
    const int* srcs[2] = {(const int*)d_in[6], (const int*)d_in[10]};
    const int* dsts[2] = {(const int*)d_in[7], (const int*)d_in[11]};
    const int* ets[2] = {(const int*)d_in[8], (const int*)d_in[12]};
    const float* norms[2] = {(const float*)d_in[9], (const float*)d_in[13]};
    const int* pg_head = (const int*)d_in[14];
    const int* pg_tail = (const int*)d_in[15];
    const int* pg_et = (const int*)d_in[16];
    const int* ng_head = (const int*)d_in[17];
    const int* ng_tail = (const int*)d_in[18];

    int E = in_sizes[6];
    int P = in_sizes[14];
    int NN = in_sizes[0] / DIM;
    float* out = (float*)d_out;

    char* w = (char*)d_ws;
    auto alloc = [&](size_t b) { char* p = w; w += (b + 255) & ~(size_t)255; return p; };
    ushort* Wt = (ushort*)alloc((size_t)2 * RREL * DIM * DIM * 2);
    ushort* hb = (ushort*)alloc((size_t)NN * DIM * 2);
    ushort* hb2 = (ushort*)alloc((size_t)NN * DIM * 2);
    float* agg = (float*)alloc((size_t)NN * DIM * 4);
    int* src_s = (int*)alloc((size_t)E * 4);
    int* dst_s = (int*)alloc((size_t)E * 4);
    float* norm_s = (float*)alloc((size_t)E * 4);
    int* hist = (int*)alloc(RREL * 4);
    int* offsets = (int*)alloc((RREL + 1) * 4);
    int* cursor = (int*)alloc(RREL * 4);
    int* ntiles = (int*)alloc(4);
    int maxtiles = E / TM + RREL + 1;
    int2* tiles = (int2*)alloc((size_t)maxtiles * 8);

    build_w_kernel<<<(2 * RREL * DIM * DIM) / 256, 256, 0, stream>>>(coeff, basis, Wt);

    for (int g = 0; g < 2; ++g) {
        float* hout = out + (size_t)5 * P * DIM + (size_t)g * NN * DIM;
        tobf16_kernel<<<(NN * DIM / 8 + 255) / 256, 256, 0, stream>>>(feats[g], hb, NN * DIM / 8);
        hipMemsetAsync(hist, 0, RREL * 4, stream);
        hist_kernel<<<512, 256, 0, stream>>>(ets[g], E, hist);
        scan_kernel<<<1, 64, 0, stream>>>(hist, offsets, cursor, tiles, ntiles);
        scatter_kernel<<<(E + 255) / 256, 256, 0, stream>>>(srcs[g], dsts[g], ets[g], norms[g], E,
                                                            cursor, src_s, dst_s, norm_s);
        for (int l = 0; l < 2; ++l) {
            hipMemsetAsync(agg, 0, (size_t)NN * DIM * 4, stream);
            gemm_scatter_kernel<<<maxtiles, 256, 0, stream>>>(
                l ? hb2 : hb, Wt + (size_t)l * RREL * DIM * DIM, src_s, dst_s, norm_s, tiles,
                ntiles, offsets, agg);
            bias_relu_kernel<<<(NN * DIM / 4 + 255) / 256, 256, 0, stream>>>(
                agg, bias + l * DIM, l ? hout : nullptr, l ? nullptr : hb2, NN * DIM / 4);
        }
    }

    const float* p_h = out + (size_t)5 * P * DIM;
    const float* n_h = p_h + (size_t)NN * DIM;
    long gtotal = (long)5 * P * 32;
    gather_kernel<<<(int)((gtotal + 255) / 256), 256, 0, stream>>>(
        p_h, n_h, w_relation, pg_head, pg_tail, pg_et, ng_head, ng_tail, out, P);
}

// Round 2
// 1053.199 us; speedup vs baseline: 1.2728x; 1.2728x over previous
//
#include <hip/hip_runtime.h>

typedef __attribute__((ext_vector_type(8))) short short8;
typedef __attribute__((ext_vector_type(4))) float f32x4;

#define DIM 128
#define RREL 32
#define TM 64

__device__ __forceinline__ ushort f2bf(float f) {
    unsigned u = __builtin_bit_cast(unsigned, f);
    u = (u + 0x7FFFu + ((u >> 16) & 1u)) >> 16;
    return (ushort)u;
}
__device__ __forceinline__ float bf2f(ushort u) {
    return __builtin_bit_cast(float, ((unsigned)u) << 16);
}

// Wt[l][r][n][k] = sum_b coeff[l,r,b] * basis[l,b,k,n]   (bf16, transposed for MFMA B-frag)
__global__ __launch_bounds__(256) void build_w_kernel(const float* __restrict__ coeff,
                                                      const float* __restrict__ basis,
                                                      ushort* __restrict__ Wt) {
    int idx = blockIdx.x * 256 + threadIdx.x;   // [l][r][n][k], k fast
    int k = idx & 127;
    int n = (idx >> 7) & 127;
    int lr = idx >> 14;                          // l*32 + r
    int l = lr >> 5;
    const float* cb = coeff + lr * 8;
    const float* bb = basis + (size_t)l * 8 * 16384 + k * 128 + n;
    float s = 0.f;
#pragma unroll
    for (int b = 0; b < 8; ++b) s += cb[b] * bb[(size_t)b * 16384];
    Wt[idx] = f2bf(s);
}

__global__ __launch_bounds__(256) void tobf16_kernel(const float* __restrict__ in,
                                                     ushort* __restrict__ out, int n8) {
    int i = blockIdx.x * 256 + threadIdx.x;
    if (i >= n8) return;
    const float4* p = (const float4*)in + 2 * (size_t)i;
    float4 a = p[0], b = p[1];
    unsigned w0 = f2bf(a.x) | ((unsigned)f2bf(a.y) << 16);
    unsigned w1 = f2bf(a.z) | ((unsigned)f2bf(a.w) << 16);
    unsigned w2 = f2bf(b.x) | ((unsigned)f2bf(b.y) << 16);
    unsigned w3 = f2bf(b.z) | ((unsigned)f2bf(b.w) << 16);
    ((uint4*)out)[i] = make_uint4(w0, w1, w2, w3);
}

// ---------------- new path: etype-hist + dst-hist in one pass ----------------
__global__ __launch_bounds__(256) void hist2_kernel(const int* __restrict__ et,
                                                    const int* __restrict__ dst, int E,
                                                    int* __restrict__ eh, int* __restrict__ dh) {
    __shared__ int lh[RREL];
    if (threadIdx.x < RREL) lh[threadIdx.x] = 0;
    __syncthreads();
    for (int i = blockIdx.x * 256 + threadIdx.x; i < E; i += gridDim.x * 256) {
        atomicAdd(&lh[et[i]], 1);
        atomicAdd(&dh[dst[i]], 1);
    }
    __syncthreads();
    if (threadIdx.x < RREL) atomicAdd(&eh[threadIdx.x], lh[threadIdx.x]);
}

// etype scan + tile list + dst scan (30000 bins) in one block
__global__ __launch_bounds__(1024) void scan2_kernel(const int* __restrict__ eh,
                                                     const int* __restrict__ dh, int NN, int E,
                                                     int* __restrict__ eoff, int* __restrict__ ecur,
                                                     int2* __restrict__ tiles, int* __restrict__ ntiles,
                                                     int* __restrict__ doff, int* __restrict__ dcur) {
    __shared__ int part[1024];
    __shared__ int eo[RREL + 1], ts[RREL + 1];
    int t = threadIdx.x;
    int chunk = (NN + 1023) >> 10;
    int b0 = t * chunk, b1 = b0 + chunk;
    if (b0 > NN) b0 = NN;
    if (b1 > NN) b1 = NN;
    int s = 0;
    for (int i = b0; i < b1; ++i) s += dh[i];
    part[t] = s;
    __syncthreads();
    for (int off = 1; off < 1024; off <<= 1) {
        int v = (t >= off) ? part[t - off] : 0;
        __syncthreads();
        part[t] += v;
        __syncthreads();
    }
    int run = part[t] - s;   // exclusive prefix
    for (int i = b0; i < b1; ++i) {
        doff[i] = run; dcur[i] = run; run += dh[i];
    }
    if (t == 0) {
        doff[NN] = E;
        int sA = 0, tt = 0;
        for (int r = 0; r < RREL; ++r) {
            eo[r] = sA; ts[r] = tt;
            sA += eh[r]; tt += (eh[r] + TM - 1) / TM;
        }
        eo[RREL] = sA; ts[RREL] = tt;
        *ntiles = tt;
        eoff[RREL] = sA;
    }
    __syncthreads();
    if (t < RREL) {
        eoff[t] = eo[t]; ecur[t] = eo[t];
        int nt = ts[t + 1] - ts[t];
        for (int i = 0; i < nt; ++i) tiles[ts[t] + i] = make_int2(t, eo[t] + i * TM);
    }
}

// etype-sort scatter + dst-rank (output position) in one pass
__global__ __launch_bounds__(256) void scatter2_kernel(const int* __restrict__ src,
                                                       const int* __restrict__ dst,
                                                       const int* __restrict__ et,
                                                       const float* __restrict__ norm, int E,
                                                       int* __restrict__ ecur, int* __restrict__ dcur,
                                                       int* __restrict__ src_s,
                                                       float* __restrict__ norm_s,
                                                       int* __restrict__ opos_s) {
    __shared__ int lh[RREL];
    __shared__ int lbase[RREL];
    int i = blockIdx.x * 256 + threadIdx.x;
    if (threadIdx.x < RREL) lh[threadIdx.x] = 0;
    __syncthreads();
    int r = 0, rank = 0;
    bool valid = (i < E);
    if (valid) { r = et[i]; rank = atomicAdd(&lh[r], 1); }
    __syncthreads();
    if (threadIdx.x < RREL) {
        int c = lh[threadIdx.x];
        if (c > 0) lbase[threadIdx.x] = atomicAdd(&ecur[threadIdx.x], c);
    }
    __syncthreads();
    if (valid) {
        int p = lbase[r] + rank;
        src_s[p] = src[i];
        norm_s[p] = norm[i];
        opos_s[p] = atomicAdd(&dcur[dst[i]], 1);
    }
}

// One block = one (relation, 64-edge) tile. msg[opos] = bf16((gather(h) @ W_r) * norm), non-atomic.
__global__ __launch_bounds__(256) void gemm_msg_kernel(
    const ushort* __restrict__ hb, const ushort* __restrict__ Wt,
    const int* __restrict__ src_s, const int* __restrict__ opos_s,
    const float* __restrict__ norm_s, const int2* __restrict__ tiles,
    const int* __restrict__ ntiles, const int* __restrict__ offsets,
    ushort* __restrict__ msg) {
    __shared__ char smem[49152];            // A:16K | B:32K ; epilogue C(bf16):16K aliases A
    __shared__ int oposl[TM];
    __shared__ float morml[TM];

    int bx = blockIdx.x;
    if (bx >= *ntiles) return;
    int2 ti = tiles[bx];
    int r = ti.x, row0 = ti.y;
    int rows = offsets[r + 1] - row0;
    if (rows > TM) rows = TM;

    int t = threadIdx.x;
    if (t < rows) { oposl[t] = opos_s[row0 + t]; morml[t] = norm_s[row0 + t]; }

    const int4* Wg = (const int4*)(Wt + (size_t)r * DIM * DIM);
    int4* Bv = (int4*)(smem + 16384);
#pragma unroll
    for (int c = t; c < DIM * DIM / 8; c += 256) {
        int n = c >> 4, ci = c & 15;
        Bv[(n * 16 + ci) ^ (n & 7)] = Wg[c];
    }
    int4* Av = (int4*)smem;
#pragma unroll
    for (int c = t; c < TM * DIM / 8; c += 256) {
        int row = c >> 4, ci = c & 15;
        int e = row0 + (row < rows ? row : rows - 1);
        int s = src_s[e];
        Av[(row * 16 + ci) ^ (row & 7)] = ((const int4*)(hb + (size_t)s * DIM))[ci];
    }
    __syncthreads();

    int w = t >> 6, l = t & 63;
    int wr = w & 1, wc = w >> 1;          // 2x2 wave grid: 32 rows x 64 cols per wave
    int lr16 = l & 15, lhi = l >> 4;

    f32x4 acc[2][4];
#pragma unroll
    for (int m = 0; m < 2; ++m)
#pragma unroll
        for (int n16 = 0; n16 < 4; ++n16) acc[m][n16] = (f32x4)0.f;

    const short8* As = (const short8*)smem;
    const short8* Bs = (const short8*)(smem + 16384);
#pragma unroll
    for (int k4 = 0; k4 < 4; ++k4) {
        int kc = k4 * 4 + lhi;
        int ar0 = wr * 32 + lr16;
        int ar1 = ar0 + 16;
        short8 a0 = As[(ar0 * 16 + kc) ^ (ar0 & 7)];
        short8 a1 = As[(ar1 * 16 + kc) ^ (ar1 & 7)];
#pragma unroll
        for (int n16 = 0; n16 < 4; ++n16) {
            int n = wc * 64 + n16 * 16 + lr16;
            short8 b = Bs[(n * 16 + kc) ^ (n & 7)];
            acc[0][n16] = __builtin_amdgcn_mfma_f32_16x16x32_bf16(a0, b, acc[0][n16], 0, 0, 0);
            acc[1][n16] = __builtin_amdgcn_mfma_f32_16x16x32_bf16(a1, b, acc[1][n16], 0, 0, 0);
        }
    }

    __syncthreads();                          // all waves done reading A/B
    ushort* Cl = (ushort*)smem;               // bf16 C tile, chunk-swizzled like A
#pragma unroll
    for (int m = 0; m < 2; ++m) {
#pragma unroll
        for (int j = 0; j < 4; ++j) {
            int row = wr * 32 + m * 16 + lhi * 4 + j;
            float nm = morml[row];
#pragma unroll
            for (int n16 = 0; n16 < 4; ++n16) {
                int col = wc * 64 + n16 * 16 + lr16;
                Cl[(row * 128 + col) ^ ((row & 7) << 3)] = f2bf(acc[m][n16][j] * nm);
            }
        }
    }
    __syncthreads();
    const int4* Cv = (const int4*)smem;
#pragma unroll
    for (int i = 0; i < 4; ++i) {
        int idx = i * 256 + t;
        int row = idx >> 4, ci = idx & 15;    // 16 int4 per 256B bf16 row
        if (row < rows) {
            int4 v = Cv[(row * 16 + ci) ^ (row & 7)];
            ((int4*)(msg + (size_t)oposl[row] * DIM))[ci] = v;
        }
    }
}

// segment-sum over dst-contiguous msg rows, fused bias+relu, writes f32 and/or bf16
__global__ __launch_bounds__(256) void segsum_kernel(const ushort* __restrict__ msg,
                                                     const int* __restrict__ doff,
                                                     const float* __restrict__ bias,
                                                     float* __restrict__ of32,
                                                     ushort* __restrict__ obf, int NN) {
    int d = blockIdx.x * 8 + (threadIdx.x >> 5);
    if (d >= NN) return;
    int lane = threadIdx.x & 31;
    int s0 = doff[d], s1 = doff[d + 1];
    float a0 = 0.f, a1 = 0.f, a2 = 0.f, a3 = 0.f;
    for (int j = s0; j < s1; ++j) {
        ushort4 v = *(const ushort4*)(msg + (size_t)j * DIM + lane * 4);
        a0 += bf2f(v.x); a1 += bf2f(v.y); a2 += bf2f(v.z); a3 += bf2f(v.w);
    }
    int c = lane * 4;
    a0 = fmaxf(a0 + bias[c], 0.f);
    a1 = fmaxf(a1 + bias[c + 1], 0.f);
    a2 = fmaxf(a2 + bias[c + 2], 0.f);
    a3 = fmaxf(a3 + bias[c + 3], 0.f);
    if (of32) ((float4*)(of32 + (size_t)d * DIM))[lane] = make_float4(a0, a1, a2, a3);
    if (obf) {
        ushort4 o; o.x = f2bf(a0); o.y = f2bf(a1); o.z = f2bf(a2); o.w = f2bf(a3);
        *(ushort4*)(obf + (size_t)d * DIM + c) = o;
    }
}

// ---------------- old (fallback) path kernels ----------------
__global__ __launch_bounds__(256) void hist_kernel(const int* __restrict__ et, int E,
                                                   int* __restrict__ hist) {
    __shared__ int lh[RREL];
    if (threadIdx.x < RREL) lh[threadIdx.x] = 0;
    __syncthreads();
    for (int i = blockIdx.x * 256 + threadIdx.x; i < E; i += gridDim.x * 256)
        atomicAdd(&lh[et[i]], 1);
    __syncthreads();
    if (threadIdx.x < RREL) atomicAdd(&hist[threadIdx.x], lh[threadIdx.x]);
}

__global__ void scan_kernel(const int* __restrict__ hist, int* __restrict__ offsets,
                            int* __restrict__ cursor, int2* __restrict__ tiles,
                            int* __restrict__ ntiles) {
    __shared__ int off[RREL + 1];
    __shared__ int ts[RREL + 1];
    if (threadIdx.x == 0) {
        int s = 0, t = 0;
        for (int r = 0; r < RREL; ++r) {
            off[r] = s; ts[r] = t;
            s += hist[r]; t += (hist[r] + TM - 1) / TM;
        }
        off[RREL] = s; ts[RREL] = t;
        *ntiles = t;
    }
    __syncthreads();
    int r = threadIdx.x;
    if (r < RREL) {
        offsets[r] = off[r];
        cursor[r] = off[r];
        int nt = ts[r + 1] - ts[r];
        for (int i = 0; i < nt; ++i) tiles[ts[r] + i] = make_int2(r, off[r] + i * TM);
    }
    if (r == 0) offsets[RREL] = off[RREL];
}

__global__ __launch_bounds__(256) void scatter_kernel(const int* __restrict__ src,
                                                      const int* __restrict__ dst,
                                                      const int* __restrict__ et,
                                                      const float* __restrict__ norm, int E,
                                                      int* __restrict__ cursor,
                                                      int* __restrict__ src_s,
                                                      int* __restrict__ dst_s,
                                                      float* __restrict__ norm_s) {
    __shared__ int lh[RREL];
    __shared__ int lbase[RREL];
    int i = blockIdx.x * 256 + threadIdx.x;
    if (threadIdx.x < RREL) lh[threadIdx.x] = 0;
    __syncthreads();
    int r = 0, rank = 0;
    bool valid = (i < E);
    if (valid) { r = et[i]; rank = atomicAdd(&lh[r], 1); }
    __syncthreads();
    if (threadIdx.x < RREL) {
        int c = lh[threadIdx.x];
        if (c > 0) lbase[threadIdx.x] = atomicAdd(&cursor[threadIdx.x], c);
    }
    __syncthreads();
    if (valid) {
        int p = lbase[r] + rank;
        src_s[p] = src[i]; dst_s[p] = dst[i]; norm_s[p] = norm[i];
    }
}

__global__ __launch_bounds__(256) void gemm_scatter_kernel(
    const ushort* __restrict__ hb, const ushort* __restrict__ Wt,
    const int* __restrict__ src_s, const int* __restrict__ dst_s,
    const float* __restrict__ norm_s, const int2* __restrict__ tiles,
    const int* __restrict__ ntiles, const int* __restrict__ offsets,
    float* __restrict__ agg) {
    __shared__ ushort Alds[TM * DIM];
    __shared__ ushort Blds[DIM * DIM];
    __shared__ int dstl[TM];
    __shared__ float morml[TM];

    int bx = blockIdx.x;
    if (bx >= *ntiles) return;
    int2 ti = tiles[bx];
    int r = ti.x, row0 = ti.y;
    int rows = offsets[r + 1] - row0;
    if (rows > TM) rows = TM;

    int t = threadIdx.x;
    if (t < rows) { dstl[t] = dst_s[row0 + t]; morml[t] = norm_s[row0 + t]; }

    const int4* Wg = (const int4*)(Wt + (size_t)r * DIM * DIM);
    int4* Bv = (int4*)Blds;
#pragma unroll
    for (int c = t; c < DIM * DIM / 8; c += 256) {
        int n = c >> 4, ci = c & 15;
        Bv[(n * 16 + ci) ^ (n & 7)] = Wg[c];
    }
    int4* Av = (int4*)Alds;
#pragma unroll
    for (int c = t; c < TM * DIM / 8; c += 256) {
        int row = c >> 4, ci = c & 15;
        int e = row0 + (row < rows ? row : rows - 1);
        int s = src_s[e];
        Av[(row * 16 + ci) ^ (row & 7)] = ((const int4*)(hb + (size_t)s * DIM))[ci];
    }
    __syncthreads();

    int w = t >> 6, l = t & 63;
    int wr = w & 1, wc = w >> 1;
    int lr16 = l & 15, lhi = l >> 4;

    f32x4 acc[2][4];
#pragma unroll
    for (int m = 0; m < 2; ++m)
#pragma unroll
        for (int n16 = 0; n16 < 4; ++n16) acc[m][n16] = (f32x4)0.f;

    const short8* As = (const short8*)Alds;
    const short8* Bs = (const short8*)Blds;
#pragma unroll
    for (int k4 = 0; k4 < 4; ++k4) {
        int kc = k4 * 4 + lhi;
        int ar0 = wr * 32 + lr16;
        int ar1 = ar0 + 16;
        short8 a0 = As[(ar0 * 16 + kc) ^ (ar0 & 7)];
        short8 a1 = As[(ar1 * 16 + kc) ^ (ar1 & 7)];
#pragma unroll
        for (int n16 = 0; n16 < 4; ++n16) {
            int n = wc * 64 + n16 * 16 + lr16;
            short8 b = Bs[(n * 16 + kc) ^ (n & 7)];
            acc[0][n16] = __builtin_amdgcn_mfma_f32_16x16x32_bf16(a0, b, acc[0][n16], 0, 0, 0);
            acc[1][n16] = __builtin_amdgcn_mfma_f32_16x16x32_bf16(a1, b, acc[1][n16], 0, 0, 0);
        }
    }

#pragma unroll
    for (int m = 0; m < 2; ++m) {
#pragma unroll
        for (int j = 0; j < 4; ++j) {
            int row = wr * 32 + m * 16 + lhi * 4 + j;
            if (row < rows) {
                float nm = morml[row];
                float* ag = agg + (size_t)dstl[row] * DIM;
#pragma unroll
                for (int n16 = 0; n16 < 4; ++n16) {
                    int col = wc * 64 + n16 * 16 + lr16;
                    atomicAdd(ag + col, acc[m][n16][j] * nm);
                }
            }
        }
    }
}

__global__ __launch_bounds__(256) void bias_relu_kernel(const float* __restrict__ agg,
                                                        const float* __restrict__ bias,
                                                        float* __restrict__ of32,
                                                        ushort* __restrict__ obf, int n4) {
    int i = blockIdx.x * 256 + threadIdx.x;
    if (i >= n4) return;
    float4 v = ((const float4*)agg)[i];
    int col = (i << 2) & 127;
    v.x = fmaxf(v.x + bias[col], 0.f);
    v.y = fmaxf(v.y + bias[col + 1], 0.f);
    v.z = fmaxf(v.z + bias[col + 2], 0.f);
    v.w = fmaxf(v.w + bias[col + 3], 0.f);
    if (of32) ((float4*)of32)[i] = v;
    if (obf) {
        unsigned w0 = f2bf(v.x) | ((unsigned)f2bf(v.y) << 16);
        unsigned w1 = f2bf(v.z) | ((unsigned)f2bf(v.w) << 16);
        ((uint2*)obf)[i] = make_uint2(w0, w1);
    }
}

__global__ __launch_bounds__(256) void gather_kernel(const float* __restrict__ p_h,
                                                     const float* __restrict__ n_h,
                                                     const float* __restrict__ w_rel,
                                                     const int* __restrict__ pg_head,
                                                     const int* __restrict__ pg_tail,
                                                     const int* __restrict__ pg_et,
                                                     const int* __restrict__ ng_head,
                                                     const int* __restrict__ ng_tail,
                                                     float* __restrict__ out, int P) {
    long tid = (long)blockIdx.x * 256 + threadIdx.x;
    long total = (long)5 * P * 32;
    if (tid >= total) return;
    int c = (int)(tid & 31);
    long rest = tid >> 5;
    int i = (int)(rest % P);
    int which = (int)(rest / P);
    const float* srcp; int row;
    switch (which) {
        case 0: srcp = p_h;   row = pg_head[i]; break;
        case 1: srcp = p_h;   row = pg_tail[i]; break;
        case 2: srcp = w_rel; row = pg_et[i];   break;
        case 3: srcp = n_h;   row = ng_head[i]; break;
        default: srcp = n_h;  row = ng_tail[i]; break;
    }
    float4 v = ((const float4*)(srcp + (size_t)row * DIM))[c];
    ((float4*)out)[((size_t)which * P + i) * 32 + c] = v;
}

extern "C" void kernel_launch(void* const* d_in, const int* in_sizes, int n_in,
                              void* d_out, int out_size, void* d_ws, size_t ws_size,
                              hipStream_t stream) {
    const float* feats[2] = {(const float*)d_in[0], (const float*)d_in[1]};
    const float* w_relation = (const float*)d_in[2];
    const float* coeff = (const float*)d_in[3];
    const float* basis = (const float*)d_in[4];
    const float* bias = (const float*)d_in[5];
    const int* srcs[2] = {(const int*)d_in[6], (const int*)d_in[10]};
    const int* dsts[2] = {(const int*)d_in[7], (const int*)d_in[11]};
    const int* ets[2] = {(const int*)d_in[8], (const int*)d_in[12]};
    const float* norms[2] = {(const float*)d_in[9], (const float*)d_in[13]};
    const int* pg_head = (const int*)d_in[14];
    const int* pg_tail = (const int*)d_in[15];
    const int* pg_et = (const int*)d_in[16];
    const int* ng_head = (const int*)d_in[17];
    const int* ng_tail = (const int*)d_in[18];

    int E = in_sizes[6];
    int P = in_sizes[14];
    int NN = in_sizes[0] / DIM;
    float* out = (float*)d_out;
    int maxtiles = E / TM + RREL + 1;

    auto al = [](size_t b) { return (b + 255) & ~(size_t)255; };
    size_t need = al((size_t)2 * RREL * DIM * DIM * 2)   // Wt
                + al((size_t)NN * DIM * 2) * 2           // hb, hb2
                + al((size_t)E * 4) * 3                  // src_s, norm_s, opos_s
                + al(RREL * 4) * 2 + al((RREL + 1) * 4) + al(4)
                + al((size_t)maxtiles * 8)
                + al((size_t)NN * 4) * 2 + al((size_t)(NN + 1) * 4)
                + al((size_t)E * DIM * 2);               // msg

    char* w = (char*)d_ws;
    auto alloc = [&](size_t b) { char* p = w; w += (b + 255) & ~(size_t)255; return p; };

    if (need <= ws_size) {
        // ---------------- new path: sorted messages, no atomics ----------------
        ushort* Wt = (ushort*)alloc((size_t)2 * RREL * DIM * DIM * 2);
        ushort* hb = (ushort*)alloc((size_t)NN * DIM * 2);
        ushort* hb2 = (ushort*)alloc((size_t)NN * DIM * 2);
        int* src_s = (int*)alloc((size_t)E * 4);
        float* norm_s = (float*)alloc((size_t)E * 4);
        int* opos_s = (int*)alloc((size_t)E * 4);
        int* ehist = (int*)alloc(RREL * 4);
        int* ecur = (int*)alloc(RREL * 4);
        int* eoff = (int*)alloc((RREL + 1) * 4);
        int* ntiles = (int*)alloc(4);
        int2* tiles = (int2*)alloc((size_t)maxtiles * 8);
        int* dhist = (int*)alloc((size_t)NN * 4);
        int* dcur = (int*)alloc((size_t)NN * 4);
        int* doff = (int*)alloc((size_t)(NN + 1) * 4);
        ushort* msg = (ushort*)alloc((size_t)E * DIM * 2);

        build_w_kernel<<<(2 * RREL * DIM * DIM) / 256, 256, 0, stream>>>(coeff, basis, Wt);

        for (int g = 0; g < 2; ++g) {
            float* hout = out + (size_t)5 * P * DIM + (size_t)g * NN * DIM;
            tobf16_kernel<<<(NN * DIM / 8 + 255) / 256, 256, 0, stream>>>(feats[g], hb,
                                                                          NN * DIM / 8);
            hipMemsetAsync(ehist, 0, RREL * 4, stream);
            hipMemsetAsync(dhist, 0, (size_t)NN * 4, stream);
            hist2_kernel<<<512, 256, 0, stream>>>(ets[g], dsts[g], E, ehist, dhist);
            scan2_kernel<<<1, 1024, 0, stream>>>(ehist, dhist, NN, E, eoff, ecur, tiles, ntiles,
                                                 doff, dcur);
            scatter2_kernel<<<(E + 255) / 256, 256, 0, stream>>>(
                srcs[g], dsts[g], ets[g], norms[g], E, ecur, dcur, src_s, norm_s, opos_s);
            for (int l = 0; l < 2; ++l) {
                gemm_msg_kernel<<<maxtiles, 256, 0, stream>>>(
                    l ? hb2 : hb, Wt + (size_t)l * RREL * DIM * DIM, src_s, opos_s, norm_s,
                    tiles, ntiles, eoff, msg);
                segsum_kernel<<<(NN + 7) / 8, 256, 0, stream>>>(
                    msg, doff, bias + l * DIM, l ? hout : nullptr, l ? nullptr : hb2, NN);
            }
        }
    } else {
        // ---------------- fallback: atomic aggregation path ----------------
        ushort* Wt = (ushort*)alloc((size_t)2 * RREL * DIM * DIM * 2);
        ushort* hb = (ushort*)alloc((size_t)NN * DIM * 2);
        ushort* hb2 = (ushort*)alloc((size_t)NN * DIM * 2);
        float* agg = (float*)alloc((size_t)NN * DIM * 4);
        int* src_s = (int*)alloc((size_t)E * 4);
        int* dst_s = (int*)alloc((size_t)E * 4);
        float* norm_s = (float*)alloc((size_t)E * 4);
        int* hist = (int*)alloc(RREL * 4);
        int* offsets = (int*)alloc((RREL + 1) * 4);
        int* cursor = (int*)alloc(RREL * 4);
        int* ntiles = (int*)alloc(4);
        int2* tiles = (int2*)alloc((size_t)maxtiles * 8);

        build_w_kernel<<<(2 * RREL * DIM * DIM) / 256, 256, 0, stream>>>(coeff, basis, Wt);

        for (int g = 0; g < 2; ++g) {
            float* hout = out + (size_t)5 * P * DIM + (size_t)g * NN * DIM;
            tobf16_kernel<<<(NN * DIM / 8 + 255) / 256, 256, 0, stream>>>(feats[g], hb,
                                                                          NN * DIM / 8);
            hipMemsetAsync(hist, 0, RREL * 4, stream);
            hist_kernel<<<512, 256, 0, stream>>>(ets[g], E, hist);
            scan_kernel<<<1, 64, 0, stream>>>(hist, offsets, cursor, tiles, ntiles);
            scatter_kernel<<<(E + 255) / 256, 256, 0, stream>>>(srcs[g], dsts[g], ets[g],
                                                                norms[g], E, cursor, src_s,
                                                                dst_s, norm_s);
            for (int l = 0; l < 2; ++l) {
                hipMemsetAsync(agg, 0, (size_t)NN * DIM * 4, stream);
                gemm_scatter_kernel<<<maxtiles, 256, 0, stream>>>(
                    l ? hb2 : hb, Wt + (size_t)l * RREL * DIM * DIM, src_s, dst_s, norm_s,
                    tiles, ntiles, offsets, agg);
                bias_relu_kernel<<<(NN * DIM / 4 + 255) / 256, 256, 0, stream>>>(
                    agg, bias + l * DIM, l ? hout : nullptr, l ? nullptr : hb2, NN * DIM / 4);
            }
        }
    }

    const float* p_h = out + (size_t)5 * P * DIM;
    const float* n_h = p_h + (size_t)NN * DIM;
    long gtotal = (long)5 * P * 32;
    gather_kernel<<<(int)((gtotal + 255) / 256), 256, 0, stream>>>(
        p_h, n_h, w_relation, pg_head, pg_tail, pg_et, ng_head, ng_tail, out, P);
}